// Round 1
// baseline (2464.877 us; speedup 1.0000x reference)
//
#include <hip/hip_runtime.h>
#include <math.h>

#define NBR 4
#define NLAY 3
#define Bk 4
#define Tk 1024
#define DIN 32
#define DMODEL 128
#define DINNER 256
#define DSTATE 16
#define DTRANK 8
#define EMBEDk 64
#define BT (Bk*Tk)          /* 4096 rows per branch */
#define EPSF 1e-7f
#define MAXNF 10.0f

__device__ __forceinline__ float siluf(float x){ return x / (1.f + __expf(-x)); }
__device__ __forceinline__ float softplusf(float x){ return (x > 20.f) ? x : log1pf(__expf(x)); }

// ---------------------------------------------------------------------------
// Generic fp32 SGEMM: C = A(MxK) @ B(KxN), 64x64 tile, Kc=32, 4x4 per thread.
// MODE 0: xz epilogue -> col<256 to C0 (xp), col>=256 to C1 (silu(z))
// MODE 1: plain store to C0 (ldc)
// MODE 2: store C0 + bias[col]
// M,N multiples of 64; K multiple of 32 (here: 32/128/256). No bounds checks.
// ---------------------------------------------------------------------------
template<int MODE>
__global__ __launch_bounds__(256) void sgemm_k(
    const float* __restrict__ A, int lda, long aBr,
    const float* __restrict__ Bw, int ldb, long bBr,
    float* __restrict__ C0, float* __restrict__ C1, long cBr, int ldc,
    const float* __restrict__ bias, long biasBr, int K)
{
    const int br = blockIdx.z;
    A  += (long)br * aBr;
    Bw += (long)br * bBr;
    C0 += (long)br * cBr;
    if (MODE == 0) C1 += (long)br * cBr;
    if (MODE == 2) bias += (long)br * biasBr;
    const int m0 = blockIdx.x * 64, n0 = blockIdx.y * 64;
    __shared__ float As[32][68];   // [k][m], pitch 68 floats (272B, 16B aligned)
    __shared__ float Bs[32][68];   // [k][n]
    const int tid = threadIdx.x;
    const int tx = tid & 15, ty = tid >> 4;
    float acc[4][4] = {};
    for (int kc = 0; kc < K; kc += 32) {
        #pragma unroll
        for (int it = 0; it < 2; ++it) {
            int id = tid + it * 256;
            int r = id >> 3, c4 = (id & 7) << 2;
            float4 v = *(const float4*)(A + (long)(m0 + r) * lda + kc + c4);
            As[c4+0][r] = v.x; As[c4+1][r] = v.y; As[c4+2][r] = v.z; As[c4+3][r] = v.w;
            int rb = id >> 4, cb = (id & 15) << 2;
            *(float4*)&Bs[rb][cb] = *(const float4*)(Bw + (long)(kc + rb) * ldb + n0 + cb);
        }
        __syncthreads();
        #pragma unroll
        for (int kk = 0; kk < 32; ++kk) {
            float4 a4 = *(const float4*)&As[kk][ty << 2];
            float4 b4 = *(const float4*)&Bs[kk][tx << 2];
            float av[4] = {a4.x, a4.y, a4.z, a4.w};
            float bv[4] = {b4.x, b4.y, b4.z, b4.w};
            #pragma unroll
            for (int i = 0; i < 4; ++i)
                #pragma unroll
                for (int j = 0; j < 4; ++j)
                    acc[i][j] = fmaf(av[i], bv[j], acc[i][j]);
        }
        __syncthreads();
    }
    #pragma unroll
    for (int i = 0; i < 4; ++i) {
        int row = m0 + (ty << 2) + i;
        #pragma unroll
        for (int j = 0; j < 4; ++j) {
            int col = n0 + (tx << 2) + j;
            float v = acc[i][j];
            if (MODE == 0) {
                if (col < DINNER) C0[(long)row * DINNER + col] = v;
                else              C1[(long)row * DINNER + (col - DINNER)] = siluf(v);
            } else if (MODE == 1) {
                C0[(long)row * ldc + col] = v;
            } else {
                C0[(long)row * ldc + col] = v + bias[col];
            }
        }
    }
}

// ---------------------------------------------------------------------------
// Depthwise causal conv (4 taps) + bias + silu.  One thread per (row, d).
// ---------------------------------------------------------------------------
__global__ __launch_bounds__(256) void conv_k(
    const float* __restrict__ xp, const float* __restrict__ cw,
    const float* __restrict__ cb, float* __restrict__ xc, int layer)
{
    const int br = blockIdx.y;
    const long base = (long)br * BT * DINNER;
    const int idx = blockIdx.x * 256 + threadIdx.x;   // [0, BT*DINNER)
    const int d = idx & (DINNER - 1);
    const int row = idx >> 8;
    const int t = row & (Tk - 1);
    const float4 w4 = *(const float4*)(cw + ((long)(br * NLAY + layer) * DINNER + d) * 4);
    const float wv[4] = {w4.x, w4.y, w4.z, w4.w};
    float acc = cb[(br * NLAY + layer) * DINNER + d];
    const float* xpb = xp + base + idx;
    #pragma unroll
    for (int k = 0; k < 4; ++k) {
        int tt = t + k - 3;
        if (tt >= 0) acc = fmaf(xpb[(long)(k - 3) * DINNER], wv[k], acc);
    }
    xc[base + idx] = siluf(acc);
}

// ---------------------------------------------------------------------------
// dbl = xc @ W_x (256->40); dt = softplus(dbl[:8] @ W_dt + b_dt); store B,C.
// Block = 4 waves, one row per wave.
// ---------------------------------------------------------------------------
__global__ __launch_bounds__(256) void dbl_k(
    const float* __restrict__ xc, const float* __restrict__ Wx,
    const float* __restrict__ Wdt, const float* __restrict__ bdt,
    float* __restrict__ dtb, float* __restrict__ bcb, int layer)
{
    const int br = blockIdx.y;
    const float* WxP  = Wx  + (long)(br * NLAY + layer) * DINNER * 40;
    const float* WdtP = Wdt + (long)(br * NLAY + layer) * DTRANK * DINNER;
    const float* bdtP = bdt + (long)(br * NLAY + layer) * DINNER;
    __shared__ float xcs[4][DINNER];
    __shared__ float dbls[4][40];
    const int tid = threadIdx.x;
    const int w = tid >> 6, lane = tid & 63;
    const int row = blockIdx.x * 4 + w;            // [0, BT)
    const float* xrow = xc + ((long)br * BT + row) * DINNER;
    *(float4*)&xcs[w][lane * 4] = *(const float4*)(xrow + lane * 4);
    __syncthreads();
    if (lane < 40) {
        float dot = 0.f;
        for (int k = 0; k < DINNER; ++k) dot = fmaf(xcs[w][k], WxP[k * 40 + lane], dot);
        dbls[w][lane] = dot;
    }
    __syncthreads();
    float r[DTRANK];
    #pragma unroll
    for (int i = 0; i < DTRANK; ++i) r[i] = dbls[w][i];
    #pragma unroll
    for (int i = 0; i < 4; ++i) {
        int d = i * 64 + lane;
        float tv = bdtP[d];
        #pragma unroll
        for (int k = 0; k < DTRANK; ++k) tv = fmaf(r[k], WdtP[k * DINNER + d], tv);
        dtb[((long)br * BT + row) * DINNER + d] = softplusf(tv);
    }
    if (lane < 32) bcb[((long)br * BT + row) * 32 + lane] = dbls[w][8 + lane];
}

// ---------------------------------------------------------------------------
// Selective scan.  Block = 256 threads = 256 channels, one (branch,b) per
// block, 16 states/thread in registers.  dA via powers of exp(-dt) when
// A = -(1..16) (runtime verified; generic exp fallback otherwise).
// yz = (scan_y + Dp*xc) * silu(z) written in place of xp.
// ---------------------------------------------------------------------------
__global__ __launch_bounds__(256) void scan_k(
    const float* __restrict__ dtb, const float* __restrict__ xcb,
    const float* __restrict__ bcb, const float* __restrict__ zb,
    const float* __restrict__ Alog, const float* __restrict__ Dpar,
    float* __restrict__ yz, int layer)
{
    const int b = blockIdx.x, br = blockIdx.y;
    const int d = threadIdx.x;
    const float* Ap = Alog + ((long)(br * NLAY + layer) * DINNER + d) * DSTATE;
    float Aa[16];
    bool pw = true;
    #pragma unroll
    for (int s = 0; s < 16; ++s) {
        Aa[s] = -__expf(Ap[s]);
        pw = pw && (fabsf(Aa[s] + (float)(s + 1)) < 1e-3f);
    }
    const float Dp = Dpar[(br * NLAY + layer) * DINNER + d];
    const long rbase = (long)br * BT + (long)b * Tk;
    const float* dtp = dtb + rbase * DINNER + d;
    const float* xcp = xcb + rbase * DINNER + d;
    const float* zp  = zb  + rbase * DINNER + d;
    float*       yp  = yz  + rbase * DINNER + d;
    const float* bcp = bcb + rbase * 32;
    float h[16];
    #pragma unroll
    for (int s = 0; s < 16; ++s) h[s] = 0.f;
    float dtv = dtp[0], xcv = xcp[0], zv = zp[0];
    for (int t = 0; t < Tk; ++t) {
        // prefetch next step (wraps harmlessly to t=0 on last iter)
        const int tn = (t + 1) & (Tk - 1);
        const float dtn = dtp[(long)tn * DINNER];
        const float xcn = xcp[(long)tn * DINNER];
        const float zn  = zp[(long)tn * DINNER];
        const float dtxc = dtv * xcv;
        float dA[16];
        if (pw) {
            float q = __expf(-dtv);
            dA[0] = q;            dA[1] = q * q;
            dA[2] = dA[1] * dA[0]; dA[3] = dA[1] * dA[1];
            dA[4] = dA[3] * dA[0]; dA[5] = dA[3] * dA[1];
            dA[6] = dA[3] * dA[2]; dA[7] = dA[3] * dA[3];
            #pragma unroll
            for (int s = 8; s < 16; ++s) dA[s] = dA[s - 8] * dA[7];
        } else {
            #pragma unroll
            for (int s = 0; s < 16; ++s) dA[s] = __expf(dtv * Aa[s]);
        }
        const float* bcT = bcp + t * 32;   // wave-uniform -> scalar loads
        #pragma unroll
        for (int s = 0; s < 16; ++s)
            h[s] = fmaf(dA[s], h[s], dtxc * bcT[s]);
        float y0 = 0.f, y1 = 0.f, y2 = 0.f, y3 = 0.f;
        #pragma unroll
        for (int s = 0; s < 16; s += 4) {
            y0 = fmaf(h[s+0], bcT[16+s+0], y0);
            y1 = fmaf(h[s+1], bcT[16+s+1], y1);
            y2 = fmaf(h[s+2], bcT[16+s+2], y2);
            y3 = fmaf(h[s+3], bcT[16+s+3], y3);
        }
        const float y = (y0 + y1) + (y2 + y3) + Dp * xcv;
        yp[(long)t * DINNER] = y * zv;
        dtv = dtn; xcv = xcn; zv = zn;
    }
}

// ---------------------------------------------------------------------------
// mean over T then @ W_op + b_op -> z_t directly into d_out[0..1023].
// One block per (branch, b).
// ---------------------------------------------------------------------------
__global__ __launch_bounds__(128) void meanop_k(
    const float* __restrict__ hbuf, const float* __restrict__ Wop,
    const float* __restrict__ bop, float* __restrict__ outzt)
{
    const int br = blockIdx.x >> 2, b = blockIdx.x & 3;
    const int tid = threadIdx.x;
    const float* hp = hbuf + ((long)br * BT + (long)b * Tk) * DMODEL + tid;
    float s = 0.f;
    for (int t = 0; t < Tk; ++t) s += hp[(long)t * DMODEL];
    __shared__ float hm[DMODEL];
    hm[tid] = s * (1.0f / Tk);
    __syncthreads();
    if (tid < EMBEDk) {
        float acc = bop[br * EMBEDk + tid];
        for (int k = 0; k < DMODEL; ++k)
            acc = fmaf(hm[k], Wop[(long)br * DMODEL * EMBEDk + k * EMBEDk + tid], acc);
        outzt[br * (Bk * EMBEDk) + b * EMBEDk + tid] = acc;
    }
}

// ---------------------------------------------------------------------------
// Lorentz epilogue: z_h = projx(expmap0(z_t*es)); us = logmap0(z_h);
// combined_tangent = sum us; combined_h = projx(expmap0(ct*es)).
// Tiny: one block.
// ---------------------------------------------------------------------------
__global__ __launch_bounds__(64) void final_k(
    const float* __restrict__ zt, float* __restrict__ out, const float* __restrict__ eff)
{
    const float es = tanhf(eff[0]);
    __shared__ float us[NBR][Bk][EMBEDk];
    const int t = threadIdx.x;
    if (t < 16) {
        const int br = t >> 2, b = t & 3;
        const float* z = zt + br * (Bk * EMBEDk) + b * EMBEDk;
        float n2 = 0.f;
        for (int e = 0; e < EMBEDk; ++e) { float v = z[e] * es; n2 = fmaf(v, v, n2); }
        const float n  = sqrtf(n2);
        const float nc = fminf(fmaxf(n, EPSF), MAXNF);
        const float sc = nc / fmaxf(n, EPSF);
        const float sh = sinhf(nc) / nc;
        const float fac = es * sc * sh;
        float* zh = out + 1024 + br * (Bk * (EMBEDk + 1)) + b * (EMBEDk + 1);
        float sp2 = 0.f;
        for (int e = 0; e < EMBEDk; ++e) {
            float spv = z[e] * fac;
            sp2 = fmaf(spv, spv, sp2);
            zh[1 + e] = spv;
            us[br][b][e] = spv;
        }
        const float t0 = sqrtf(1.f + sp2);
        zh[0] = t0;
        const float dd  = acoshf(fmaxf(t0, 1.f + EPSF));
        const float spn = fmaxf(sqrtf(sp2), EPSF);
        const float rr  = dd / spn;
        for (int e = 0; e < EMBEDk; ++e) us[br][b][e] *= rr;
    }
    __syncthreads();
    if (t < 4) {
        const int b = t;
        float ct[EMBEDk];
        float* cto = out + 2064 + b * EMBEDk;
        for (int e = 0; e < EMBEDk; ++e) {
            float v = us[0][b][e] + us[1][b][e] + us[2][b][e] + us[3][b][e];
            ct[e] = v; cto[e] = v;
        }
        float n2 = 0.f;
        for (int e = 0; e < EMBEDk; ++e) { float v = ct[e] * es; n2 = fmaf(v, v, n2); }
        const float n  = sqrtf(n2);
        const float nc = fminf(fmaxf(n, EPSF), MAXNF);
        const float sc = nc / fmaxf(n, EPSF);
        const float sh = sinhf(nc) / nc;
        const float fac = es * sc * sh;
        float* ch = out + 2320 + b * (EMBEDk + 1);
        float sp2 = 0.f;
        for (int e = 0; e < EMBEDk; ++e) {
            float spv = ct[e] * fac;
            sp2 = fmaf(spv, spv, sp2);
            ch[1 + e] = spv;
        }
        ch[0] = sqrtf(1.f + sp2);
    }
}

extern "C" void kernel_launch(void* const* d_in, const int* in_sizes, int n_in,
                              void* d_out, int out_size, void* d_ws, size_t ws_size,
                              hipStream_t stream)
{
    const float* X[4] = {(const float*)d_in[0], (const float*)d_in[1],
                         (const float*)d_in[2], (const float*)d_in[3]};
    const float* W_ip   = (const float*)d_in[4];
    const float* b_ip   = (const float*)d_in[5];
    const float* W_in   = (const float*)d_in[6];
    const float* conv_w = (const float*)d_in[7];
    const float* conv_b = (const float*)d_in[8];
    const float* W_x    = (const float*)d_in[9];
    const float* W_dt   = (const float*)d_in[10];
    const float* b_dt   = (const float*)d_in[11];
    const float* A_log  = (const float*)d_in[12];
    const float* D_par  = (const float*)d_in[13];
    const float* W_out  = (const float*)d_in[14];
    const float* W_op   = (const float*)d_in[15];
    const float* b_op   = (const float*)d_in[16];
    const float* eff    = (const float*)d_in[17];
    float* out = (float*)d_out;
    float* ws  = (float*)d_ws;

    // workspace layout (floats): ~77.6 MB total
    float* buf_h  = ws;                                  // 4*4096*128
    float* buf_xp = buf_h  + (long)NBR * BT * DMODEL;    // 4*4096*256 (reused as yz)
    float* buf_z  = buf_xp + (long)NBR * BT * DINNER;    // silu(z)
    float* buf_xc = buf_z  + (long)NBR * BT * DINNER;
    float* buf_dt = buf_xc + (long)NBR * BT * DINNER;
    float* buf_bc = buf_dt + (long)NBR * BT * DINNER;    // 4*4096*32

    // input projection per branch (A pointers differ): h0 = x @ W_ip + b_ip
    for (int br = 0; br < NBR; ++br) {
        sgemm_k<2><<<dim3(BT / 64, DMODEL / 64, 1), 256, 0, stream>>>(
            X[br], DIN, 0,
            W_ip + (long)br * DIN * DMODEL, DMODEL, 0,
            buf_h + (long)br * BT * DMODEL, nullptr, 0, DMODEL,
            b_ip + br * DMODEL, 0, DIN);
    }

    for (int l = 0; l < NLAY; ++l) {
        // xz = h @ W_in; split -> xp, silu(z)
        sgemm_k<0><<<dim3(BT / 64, (2 * DINNER) / 64, NBR), 256, 0, stream>>>(
            buf_h, DMODEL, (long)BT * DMODEL,
            W_in + (long)l * DMODEL * 2 * DINNER, 2 * DINNER,
            (long)NLAY * DMODEL * 2 * DINNER,
            buf_xp, buf_z, (long)BT * DINNER, 0,
            nullptr, 0, DMODEL);
        // depthwise conv + silu
        conv_k<<<dim3((BT * DINNER) / 256, NBR), 256, 0, stream>>>(
            buf_xp, conv_w, conv_b, buf_xc, l);
        // dbl -> dt, B, C
        dbl_k<<<dim3(BT / 4, NBR), 256, 0, stream>>>(
            buf_xc, W_x, W_dt, b_dt, buf_dt, buf_bc, l);
        // selective scan -> yz (into buf_xp)
        scan_k<<<dim3(Bk, NBR), 256, 0, stream>>>(
            buf_dt, buf_xc, buf_bc, buf_z, A_log, D_par, buf_xp, l);
        // h = yz @ W_out
        sgemm_k<1><<<dim3(BT / 64, DMODEL / 64, NBR), 256, 0, stream>>>(
            buf_xp, DINNER, (long)BT * DINNER,
            W_out + (long)l * DINNER * DMODEL, DMODEL,
            (long)NLAY * DINNER * DMODEL,
            buf_h, nullptr, (long)BT * DMODEL, DMODEL,
            nullptr, 0, DINNER);
    }

    // z_t -> d_out[0..1023]
    meanop_k<<<16, 128, 0, stream>>>(buf_h, W_op, b_op, out);
    // Lorentz epilogue -> d_out[1024..2579]
    final_k<<<1, 64, 0, stream>>>(out, out, eff);
}

// Round 2
// 730.967 us; speedup vs baseline: 3.3721x; 3.3721x over previous
//
#include <hip/hip_runtime.h>
#include <math.h>

#define NBR 4
#define NLAY 3
#define Bk 4
#define Tk 1024
#define DIN 32
#define DMODEL 128
#define DINNER 256
#define DSTATE 16
#define DTRANK 8
#define EMBEDk 64
#define BT (Bk*Tk)          /* 4096 rows per branch */
#define EPSF 1e-7f
#define MAXNF 10.0f
#define LCH 64              /* scan chunk length */
#define NCH (Tk/LCH)        /* 16 chunks */

__device__ __forceinline__ float siluf(float x){ return x / (1.f + __expf(-x)); }
__device__ __forceinline__ float softplusf(float x){ return (x > 20.f) ? x : log1pf(__expf(x)); }

// ---------------------------------------------------------------------------
// Generic fp32 SGEMM: C = A(MxK) @ B(KxN), 64x64 tile, Kc=32, 4x4 per thread.
// MODE 0: xz epilogue -> col<256 to C0 (xp), col>=256 to C1 (silu(z))
// MODE 1: plain store to C0 (ldc)
// MODE 2: store C0 + bias[col]
// ---------------------------------------------------------------------------
template<int MODE>
__global__ __launch_bounds__(256) void sgemm_k(
    const float* __restrict__ A, int lda, long aBr,
    const float* __restrict__ Bw, int ldb, long bBr,
    float* __restrict__ C0, float* __restrict__ C1, long cBr, int ldc,
    const float* __restrict__ bias, long biasBr, int K)
{
    const int br = blockIdx.z;
    A  += (long)br * aBr;
    Bw += (long)br * bBr;
    C0 += (long)br * cBr;
    if (MODE == 0) C1 += (long)br * cBr;
    if (MODE == 2) bias += (long)br * biasBr;
    const int m0 = blockIdx.x * 64, n0 = blockIdx.y * 64;
    __shared__ float As[32][68];
    __shared__ float Bs[32][68];
    const int tid = threadIdx.x;
    const int tx = tid & 15, ty = tid >> 4;
    float acc[4][4] = {};
    for (int kc = 0; kc < K; kc += 32) {
        #pragma unroll
        for (int it = 0; it < 2; ++it) {
            int id = tid + it * 256;
            int r = id >> 3, c4 = (id & 7) << 2;
            float4 v = *(const float4*)(A + (long)(m0 + r) * lda + kc + c4);
            As[c4+0][r] = v.x; As[c4+1][r] = v.y; As[c4+2][r] = v.z; As[c4+3][r] = v.w;
            int rb = id >> 4, cb = (id & 15) << 2;
            *(float4*)&Bs[rb][cb] = *(const float4*)(Bw + (long)(kc + rb) * ldb + n0 + cb);
        }
        __syncthreads();
        #pragma unroll
        for (int kk = 0; kk < 32; ++kk) {
            float4 a4 = *(const float4*)&As[kk][ty << 2];
            float4 b4 = *(const float4*)&Bs[kk][tx << 2];
            float av[4] = {a4.x, a4.y, a4.z, a4.w};
            float bv[4] = {b4.x, b4.y, b4.z, b4.w};
            #pragma unroll
            for (int i = 0; i < 4; ++i)
                #pragma unroll
                for (int j = 0; j < 4; ++j)
                    acc[i][j] = fmaf(av[i], bv[j], acc[i][j]);
        }
        __syncthreads();
    }
    #pragma unroll
    for (int i = 0; i < 4; ++i) {
        int row = m0 + (ty << 2) + i;
        #pragma unroll
        for (int j = 0; j < 4; ++j) {
            int col = n0 + (tx << 2) + j;
            float v = acc[i][j];
            if (MODE == 0) {
                if (col < DINNER) C0[(long)row * DINNER + col] = v;
                else              C1[(long)row * DINNER + (col - DINNER)] = siluf(v);
            } else if (MODE == 1) {
                C0[(long)row * ldc + col] = v;
            } else {
                C0[(long)row * ldc + col] = v + bias[col];
            }
        }
    }
}

// ---------------------------------------------------------------------------
// Depthwise causal conv (4 taps) + bias + silu.
// ---------------------------------------------------------------------------
__global__ __launch_bounds__(256) void conv_k(
    const float* __restrict__ xp, const float* __restrict__ cw,
    const float* __restrict__ cb, float* __restrict__ xc, int layer)
{
    const int br = blockIdx.y;
    const long base = (long)br * BT * DINNER;
    const int idx = blockIdx.x * 256 + threadIdx.x;
    const int d = idx & (DINNER - 1);
    const int row = idx >> 8;
    const int t = row & (Tk - 1);
    const float4 w4 = *(const float4*)(cw + ((long)(br * NLAY + layer) * DINNER + d) * 4);
    const float wv[4] = {w4.x, w4.y, w4.z, w4.w};
    float acc = cb[(br * NLAY + layer) * DINNER + d];
    const float* xpb = xp + base + idx;
    #pragma unroll
    for (int k = 0; k < 4; ++k) {
        int tt = t + k - 3;
        if (tt >= 0) acc = fmaf(xpb[(long)(k - 3) * DINNER], wv[k], acc);
    }
    xc[base + idx] = siluf(acc);
}

// ---------------------------------------------------------------------------
// dbl = xc @ W_x (256->40); dt = softplus(dbl[:8] @ W_dt + b_dt); store B,C.
// ---------------------------------------------------------------------------
__global__ __launch_bounds__(256) void dbl_k(
    const float* __restrict__ xc, const float* __restrict__ Wx,
    const float* __restrict__ Wdt, const float* __restrict__ bdt,
    float* __restrict__ dtb, float* __restrict__ bcb, int layer)
{
    const int br = blockIdx.y;
    const float* WxP  = Wx  + (long)(br * NLAY + layer) * DINNER * 40;
    const float* WdtP = Wdt + (long)(br * NLAY + layer) * DTRANK * DINNER;
    const float* bdtP = bdt + (long)(br * NLAY + layer) * DINNER;
    __shared__ float xcs[4][DINNER];
    __shared__ float dbls[4][40];
    const int tid = threadIdx.x;
    const int w = tid >> 6, lane = tid & 63;
    const int row = blockIdx.x * 4 + w;
    const float* xrow = xc + ((long)br * BT + row) * DINNER;
    *(float4*)&xcs[w][lane * 4] = *(const float4*)(xrow + lane * 4);
    __syncthreads();
    if (lane < 40) {
        float dot = 0.f;
        for (int k = 0; k < DINNER; ++k) dot = fmaf(xcs[w][k], WxP[k * 40 + lane], dot);
        dbls[w][lane] = dot;
    }
    __syncthreads();
    float r[DTRANK];
    #pragma unroll
    for (int i = 0; i < DTRANK; ++i) r[i] = dbls[w][i];
    #pragma unroll
    for (int i = 0; i < 4; ++i) {
        int d = i * 64 + lane;
        float tv = bdtP[d];
        #pragma unroll
        for (int k = 0; k < DTRANK; ++k) tv = fmaf(r[k], WdtP[k * DINNER + d], tv);
        dtb[((long)br * BT + row) * DINNER + d] = softplusf(tv);
    }
    if (lane < 32) bcb[((long)br * BT + row) * 32 + lane] = dbls[w][8 + lane];
}

// ---------------------------------------------------------------------------
// Chunked selective scan, pass 1: per chunk, local recurrence from h=0.
// Emits h_end[16] and sum(dt) per (br,b,chunk,d).  dA_t = exp(dt*Aa[s]), so
// the chunk decay product is exp(Aa[s]*sum dt) -- one scalar suffices.
// Record layout: scanbuf[((br*Bk+b)*NCH + c)*17*256 + slot*256 + d],
// slot 0..15 = h_end[s], slot 16 = sumdt.  Coalesced in d.
// ---------------------------------------------------------------------------
__global__ __launch_bounds__(256) void scan1_k(
    const float* __restrict__ dtb, const float* __restrict__ xcb,
    const float* __restrict__ bcb, const float* __restrict__ Alog,
    float* __restrict__ scanbuf, int layer)
{
    const int c = blockIdx.x, b = blockIdx.y, br = blockIdx.z;
    const int d = threadIdx.x;
    const float* Ap = Alog + ((long)(br * NLAY + layer) * DINNER + d) * DSTATE;
    float Aa[16];
    bool pw = true;
    #pragma unroll
    for (int s = 0; s < 16; ++s) {
        Aa[s] = -__expf(Ap[s]);
        pw = pw && (fabsf(Aa[s] + (float)(s + 1)) < 1e-3f);
    }
    const long rbase = (long)br * BT + (long)b * Tk + (long)c * LCH;
    const float* dtp = dtb + rbase * DINNER + d;
    const float* xcp = xcb + rbase * DINNER + d;
    const float* bcp = bcb + rbase * 32;
    float h[16];
    #pragma unroll
    for (int s = 0; s < 16; ++s) h[s] = 0.f;
    float sumdt = 0.f;
    float dtv = dtp[0], xcv = xcp[0];
    for (int t = 0; t < LCH; ++t) {
        const int tn = (t + 1 < LCH) ? t + 1 : LCH - 1;
        const float dtn = dtp[(long)tn * DINNER];
        const float xcn = xcp[(long)tn * DINNER];
        const float dtxc = dtv * xcv;
        sumdt += dtv;
        float dA[16];
        if (pw) {
            float q = __expf(-dtv);
            dA[0] = q;             dA[1] = q * q;
            dA[2] = dA[1] * dA[0]; dA[3] = dA[1] * dA[1];
            dA[4] = dA[3] * dA[0]; dA[5] = dA[3] * dA[1];
            dA[6] = dA[3] * dA[2]; dA[7] = dA[3] * dA[3];
            #pragma unroll
            for (int s = 8; s < 16; ++s) dA[s] = dA[s - 8] * dA[7];
        } else {
            #pragma unroll
            for (int s = 0; s < 16; ++s) dA[s] = __expf(dtv * Aa[s]);
        }
        const float* bcT = bcp + t * 32;          // wave-uniform
        #pragma unroll
        for (int s = 0; s < 16; ++s)
            h[s] = fmaf(dA[s], h[s], dtxc * bcT[s]);
        dtv = dtn; xcv = xcn;
    }
    float* sb = scanbuf + (((long)(br * Bk + b) * NCH + c) * 17) * 256 + d;
    #pragma unroll
    for (int s = 0; s < 16; ++s) sb[s * 256] = h[s];
    sb[16 * 256] = sumdt;
}

// ---------------------------------------------------------------------------
// Chunked selective scan, pass 2: fold preceding chunk records into a carry,
// re-run the chunk from the carry, compute y and yz = (y+Dp*xc)*silu(z).
// ---------------------------------------------------------------------------
__global__ __launch_bounds__(256) void scan3_k(
    const float* __restrict__ dtb, const float* __restrict__ xcb,
    const float* __restrict__ bcb, const float* __restrict__ zb,
    const float* __restrict__ Alog, const float* __restrict__ Dpar,
    const float* __restrict__ scanbuf, float* __restrict__ yz, int layer)
{
    const int c = blockIdx.x, b = blockIdx.y, br = blockIdx.z;
    const int d = threadIdx.x;
    const float* Ap = Alog + ((long)(br * NLAY + layer) * DINNER + d) * DSTATE;
    float Aa[16];
    bool pw = true;
    #pragma unroll
    for (int s = 0; s < 16; ++s) {
        Aa[s] = -__expf(Ap[s]);
        pw = pw && (fabsf(Aa[s] + (float)(s + 1)) < 1e-3f);
    }
    const float Dp = Dpar[(br * NLAY + layer) * DINNER + d];
    // ---- carry from preceding chunks ----
    float h[16];
    #pragma unroll
    for (int s = 0; s < 16; ++s) h[s] = 0.f;
    const float* sbB = scanbuf + ((long)(br * Bk + b) * NCH) * 17 * 256 + d;
    for (int cc = 0; cc < c; ++cc) {
        const float* sb = sbB + (long)cc * 17 * 256;
        const float sdt = sb[16 * 256];
        float P[16];
        if (pw) {
            float Q = __expf(-sdt);
            P[0] = Q;             P[1] = Q * Q;
            P[2] = P[1] * P[0];   P[3] = P[1] * P[1];
            P[4] = P[3] * P[0];   P[5] = P[3] * P[1];
            P[6] = P[3] * P[2];   P[7] = P[3] * P[3];
            #pragma unroll
            for (int s = 8; s < 16; ++s) P[s] = P[s - 8] * P[7];
        } else {
            #pragma unroll
            for (int s = 0; s < 16; ++s) P[s] = __expf(sdt * Aa[s]);
        }
        #pragma unroll
        for (int s = 0; s < 16; ++s)
            h[s] = fmaf(h[s], P[s], sb[s * 256]);
    }
    // ---- local chunk from carry ----
    const long rbase = (long)br * BT + (long)b * Tk + (long)c * LCH;
    const float* dtp = dtb + rbase * DINNER + d;
    const float* xcp = xcb + rbase * DINNER + d;
    const float* zp  = zb  + rbase * DINNER + d;
    float*       yp  = yz  + rbase * DINNER + d;
    const float* bcp = bcb + rbase * 32;
    float dtv = dtp[0], xcv = xcp[0], zv = zp[0];
    for (int t = 0; t < LCH; ++t) {
        const int tn = (t + 1 < LCH) ? t + 1 : LCH - 1;
        const float dtn = dtp[(long)tn * DINNER];
        const float xcn = xcp[(long)tn * DINNER];
        const float zn  = zp[(long)tn * DINNER];
        const float dtxc = dtv * xcv;
        float dA[16];
        if (pw) {
            float q = __expf(-dtv);
            dA[0] = q;             dA[1] = q * q;
            dA[2] = dA[1] * dA[0]; dA[3] = dA[1] * dA[1];
            dA[4] = dA[3] * dA[0]; dA[5] = dA[3] * dA[1];
            dA[6] = dA[3] * dA[2]; dA[7] = dA[3] * dA[3];
            #pragma unroll
            for (int s = 8; s < 16; ++s) dA[s] = dA[s - 8] * dA[7];
        } else {
            #pragma unroll
            for (int s = 0; s < 16; ++s) dA[s] = __expf(dtv * Aa[s]);
        }
        const float* bcT = bcp + t * 32;          // wave-uniform
        #pragma unroll
        for (int s = 0; s < 16; ++s)
            h[s] = fmaf(dA[s], h[s], dtxc * bcT[s]);
        float y0 = 0.f, y1 = 0.f, y2 = 0.f, y3 = 0.f;
        #pragma unroll
        for (int s = 0; s < 16; s += 4) {
            y0 = fmaf(h[s+0], bcT[16+s+0], y0);
            y1 = fmaf(h[s+1], bcT[16+s+1], y1);
            y2 = fmaf(h[s+2], bcT[16+s+2], y2);
            y3 = fmaf(h[s+3], bcT[16+s+3], y3);
        }
        const float y = (y0 + y1) + (y2 + y3) + Dp * xcv;
        yp[(long)t * DINNER] = y * zv;
        dtv = dtn; xcv = xcn; zv = zn;
    }
}

// ---------------------------------------------------------------------------
// mean over T then @ W_op + b_op -> z_t directly into d_out[0..1023].
// ---------------------------------------------------------------------------
__global__ __launch_bounds__(128) void meanop_k(
    const float* __restrict__ hbuf, const float* __restrict__ Wop,
    const float* __restrict__ bop, float* __restrict__ outzt)
{
    const int br = blockIdx.x >> 2, b = blockIdx.x & 3;
    const int tid = threadIdx.x;
    const float* hp = hbuf + ((long)br * BT + (long)b * Tk) * DMODEL + tid;
    float s = 0.f;
    for (int t = 0; t < Tk; ++t) s += hp[(long)t * DMODEL];
    __shared__ float hm[DMODEL];
    hm[tid] = s * (1.0f / Tk);
    __syncthreads();
    if (tid < EMBEDk) {
        float acc = bop[br * EMBEDk + tid];
        for (int k = 0; k < DMODEL; ++k)
            acc = fmaf(hm[k], Wop[(long)br * DMODEL * EMBEDk + k * EMBEDk + tid], acc);
        outzt[br * (Bk * EMBEDk) + b * EMBEDk + tid] = acc;
    }
}

// ---------------------------------------------------------------------------
// Lorentz epilogue.
// ---------------------------------------------------------------------------
__global__ __launch_bounds__(64) void final_k(
    const float* __restrict__ zt, float* __restrict__ out, const float* __restrict__ eff)
{
    const float es = tanhf(eff[0]);
    __shared__ float us[NBR][Bk][EMBEDk];
    const int t = threadIdx.x;
    if (t < 16) {
        const int br = t >> 2, b = t & 3;
        const float* z = zt + br * (Bk * EMBEDk) + b * EMBEDk;
        float n2 = 0.f;
        for (int e = 0; e < EMBEDk; ++e) { float v = z[e] * es; n2 = fmaf(v, v, n2); }
        const float n  = sqrtf(n2);
        const float nc = fminf(fmaxf(n, EPSF), MAXNF);
        const float sc = nc / fmaxf(n, EPSF);
        const float sh = sinhf(nc) / nc;
        const float fac = es * sc * sh;
        float* zh = out + 1024 + br * (Bk * (EMBEDk + 1)) + b * (EMBEDk + 1);
        float sp2 = 0.f;
        for (int e = 0; e < EMBEDk; ++e) {
            float spv = z[e] * fac;
            sp2 = fmaf(spv, spv, sp2);
            zh[1 + e] = spv;
            us[br][b][e] = spv;
        }
        const float t0 = sqrtf(1.f + sp2);
        zh[0] = t0;
        const float dd  = acoshf(fmaxf(t0, 1.f + EPSF));
        const float spn = fmaxf(sqrtf(sp2), EPSF);
        const float rr  = dd / spn;
        for (int e = 0; e < EMBEDk; ++e) us[br][b][e] *= rr;
    }
    __syncthreads();
    if (t < 4) {
        const int b = t;
        float ct[EMBEDk];
        float* cto = out + 2064 + b * EMBEDk;
        for (int e = 0; e < EMBEDk; ++e) {
            float v = us[0][b][e] + us[1][b][e] + us[2][b][e] + us[3][b][e];
            ct[e] = v; cto[e] = v;
        }
        float n2 = 0.f;
        for (int e = 0; e < EMBEDk; ++e) { float v = ct[e] * es; n2 = fmaf(v, v, n2); }
        const float n  = sqrtf(n2);
        const float nc = fminf(fmaxf(n, EPSF), MAXNF);
        const float sc = nc / fmaxf(n, EPSF);
        const float sh = sinhf(nc) / nc;
        const float fac = es * sc * sh;
        float* ch = out + 2320 + b * (EMBEDk + 1);
        float sp2 = 0.f;
        for (int e = 0; e < EMBEDk; ++e) {
            float spv = ct[e] * fac;
            sp2 = fmaf(spv, spv, sp2);
            ch[1 + e] = spv;
        }
        ch[0] = sqrtf(1.f + sp2);
    }
}

extern "C" void kernel_launch(void* const* d_in, const int* in_sizes, int n_in,
                              void* d_out, int out_size, void* d_ws, size_t ws_size,
                              hipStream_t stream)
{
    const float* X[4] = {(const float*)d_in[0], (const float*)d_in[1],
                         (const float*)d_in[2], (const float*)d_in[3]};
    const float* W_ip   = (const float*)d_in[4];
    const float* b_ip   = (const float*)d_in[5];
    const float* W_in   = (const float*)d_in[6];
    const float* conv_w = (const float*)d_in[7];
    const float* conv_b = (const float*)d_in[8];
    const float* W_x    = (const float*)d_in[9];
    const float* W_dt   = (const float*)d_in[10];
    const float* b_dt   = (const float*)d_in[11];
    const float* A_log  = (const float*)d_in[12];
    const float* D_par  = (const float*)d_in[13];
    const float* W_out  = (const float*)d_in[14];
    const float* W_op   = (const float*)d_in[15];
    const float* b_op   = (const float*)d_in[16];
    const float* eff    = (const float*)d_in[17];
    float* out = (float*)d_out;
    float* ws  = (float*)d_ws;

    // workspace layout (floats), ~74 MB
    float* buf_h  = ws;                                  // 4*4096*128 = 2.10M
    float* buf_xp = buf_h  + (long)NBR * BT * DMODEL;    // 4*4096*256 (reused as yz)
    float* buf_z  = buf_xp + (long)NBR * BT * DINNER;
    float* buf_xc = buf_z  + (long)NBR * BT * DINNER;
    float* buf_dt = buf_xc + (long)NBR * BT * DINNER;
    float* buf_bc = buf_dt + (long)NBR * BT * DINNER;    // 4*4096*32
    // scan chunk records alias buf_h: 4*4*16*17*256 = 1.11M floats < 2.10M.
    // buf_h is dead between the xz-GEMM (reads it) and W_out-GEMM (writes it).
    float* scanbuf = buf_h;

    // input projection per branch: h0 = x @ W_ip + b_ip
    for (int br = 0; br < NBR; ++br) {
        sgemm_k<2><<<dim3(BT / 64, DMODEL / 64, 1), 256, 0, stream>>>(
            X[br], DIN, 0,
            W_ip + (long)br * DIN * DMODEL, DMODEL, 0,
            buf_h + (long)br * BT * DMODEL, nullptr, 0, DMODEL,
            b_ip + br * DMODEL, 0, DIN);
    }

    for (int l = 0; l < NLAY; ++l) {
        // xz = h @ W_in; split -> xp, silu(z)
        sgemm_k<0><<<dim3(BT / 64, (2 * DINNER) / 64, NBR), 256, 0, stream>>>(
            buf_h, DMODEL, (long)BT * DMODEL,
            W_in + (long)l * DMODEL * 2 * DINNER, 2 * DINNER,
            (long)NLAY * DMODEL * 2 * DINNER,
            buf_xp, buf_z, (long)BT * DINNER, 0,
            nullptr, 0, DMODEL);
        // depthwise conv + silu
        conv_k<<<dim3((BT * DINNER) / 256, NBR), 256, 0, stream>>>(
            buf_xp, conv_w, conv_b, buf_xc, l);
        // dbl -> dt, B, C
        dbl_k<<<dim3(BT / 4, NBR), 256, 0, stream>>>(
            buf_xc, W_x, W_dt, b_dt, buf_dt, buf_bc, l);
        // chunked scan pass 1 (last chunk's record is never consumed -> NCH-1)
        scan1_k<<<dim3(NCH - 1, Bk, NBR), 256, 0, stream>>>(
            buf_dt, buf_xc, buf_bc, A_log, scanbuf, l);
        // chunked scan pass 2 -> yz (into buf_xp)
        scan3_k<<<dim3(NCH, Bk, NBR), 256, 0, stream>>>(
            buf_dt, buf_xc, buf_bc, buf_z, A_log, D_par, scanbuf, buf_xp, l);
        // h = yz @ W_out
        sgemm_k<1><<<dim3(BT / 64, DMODEL / 64, NBR), 256, 0, stream>>>(
            buf_xp, DINNER, (long)BT * DINNER,
            W_out + (long)l * DINNER * DMODEL, DMODEL,
            (long)NLAY * DINNER * DMODEL,
            buf_h, nullptr, (long)BT * DMODEL, DMODEL,
            nullptr, 0, DINNER);
    }

    meanop_k<<<16, 128, 0, stream>>>(buf_h, W_op, b_op, out);
    final_k<<<1, 64, 0, stream>>>(out, out, eff);
}

// Round 4
// 597.921 us; speedup vs baseline: 4.1224x; 1.2225x over previous
//
#include <hip/hip_runtime.h>
#include <math.h>

#define NBR 4
#define NLAY 3
#define Bk 4
#define Tk 1024
#define DIN 32
#define DMODEL 128
#define DINNER 256
#define DSTATE 16
#define DTRANK 8
#define EMBEDk 64
#define BT (Bk*Tk)          /* 4096 rows per branch */
#define EPSF 1e-7f
#define MAXNF 10.0f
#define LCH 64              /* scan chunk length */
#define NCH (Tk/LCH)        /* 16 chunks */
#define UF 8                /* t-loop batch (latency amortization) */

__device__ __forceinline__ float siluf(float x){ return x / (1.f + __expf(-x)); }
__device__ __forceinline__ float softplusf(float x){ return (x > 20.f) ? x : log1pf(__expf(x)); }

// dA[s] = q^(s+1) from q (A_s = -(s+1) fast path)
__device__ __forceinline__ void dA_pow(float q, float* dA){
    dA[0] = q;             dA[1] = q * q;
    dA[2] = dA[1] * dA[0]; dA[3] = dA[1] * dA[1];
    dA[4] = dA[3] * dA[0]; dA[5] = dA[3] * dA[1];
    dA[6] = dA[3] * dA[2]; dA[7] = dA[3] * dA[3];
    #pragma unroll
    for (int s = 8; s < 16; ++s) dA[s] = dA[s - 8] * dA[7];
}
// generic fallback: dA[s] = exp(dtv * Aa[s])
__device__ __forceinline__ void dA_exp(float dtv, const float* Aa, float* dA){
    #pragma unroll
    for (int s = 0; s < 16; ++s) dA[s] = __expf(dtv * Aa[s]);
}

// ---------------------------------------------------------------------------
// Generic fp32 SGEMM: C = A(MxK) @ B(KxN), 64x64 tile, Kc=32, 4x4 per thread.
// MODE 0: xz epilogue -> col<256 to C0 (xp), col>=256 to C1 (silu(z))
// MODE 1: plain store to C0 (ldc)
// MODE 2: store C0 + bias[col]
// ---------------------------------------------------------------------------
template<int MODE>
__global__ __launch_bounds__(256) void sgemm_k(
    const float* __restrict__ A, int lda, long aBr,
    const float* __restrict__ Bw, int ldb, long bBr,
    float* __restrict__ C0, float* __restrict__ C1, long cBr, int ldc,
    const float* __restrict__ bias, long biasBr, int K)
{
    const int br = blockIdx.z;
    A  += (long)br * aBr;
    Bw += (long)br * bBr;
    C0 += (long)br * cBr;
    if (MODE == 0) C1 += (long)br * cBr;
    if (MODE == 2) bias += (long)br * biasBr;
    const int m0 = blockIdx.x * 64, n0 = blockIdx.y * 64;
    __shared__ float As[32][68];
    __shared__ float Bs[32][68];
    const int tid = threadIdx.x;
    const int tx = tid & 15, ty = tid >> 4;
    float acc[4][4] = {};
    for (int kc = 0; kc < K; kc += 32) {
        #pragma unroll
        for (int it = 0; it < 2; ++it) {
            int id = tid + it * 256;
            int r = id >> 3, c4 = (id & 7) << 2;
            float4 v = *(const float4*)(A + (long)(m0 + r) * lda + kc + c4);
            As[c4+0][r] = v.x; As[c4+1][r] = v.y; As[c4+2][r] = v.z; As[c4+3][r] = v.w;
            int rb = id >> 4, cb = (id & 15) << 2;
            *(float4*)&Bs[rb][cb] = *(const float4*)(Bw + (long)(kc + rb) * ldb + n0 + cb);
        }
        __syncthreads();
        #pragma unroll
        for (int kk = 0; kk < 32; ++kk) {
            float4 a4 = *(const float4*)&As[kk][ty << 2];
            float4 b4 = *(const float4*)&Bs[kk][tx << 2];
            float av[4] = {a4.x, a4.y, a4.z, a4.w};
            float bv[4] = {b4.x, b4.y, b4.z, b4.w};
            #pragma unroll
            for (int i = 0; i < 4; ++i)
                #pragma unroll
                for (int j = 0; j < 4; ++j)
                    acc[i][j] = fmaf(av[i], bv[j], acc[i][j]);
        }
        __syncthreads();
    }
    #pragma unroll
    for (int i = 0; i < 4; ++i) {
        int row = m0 + (ty << 2) + i;
        #pragma unroll
        for (int j = 0; j < 4; ++j) {
            int col = n0 + (tx << 2) + j;
            float v = acc[i][j];
            if (MODE == 0) {
                if (col < DINNER) C0[(long)row * DINNER + col] = v;
                else              C1[(long)row * DINNER + (col - DINNER)] = siluf(v);
            } else if (MODE == 1) {
                C0[(long)row * ldc + col] = v;
            } else {
                C0[(long)row * ldc + col] = v + bias[col];
            }
        }
    }
}

// ---------------------------------------------------------------------------
// Depthwise causal conv (4 taps) + bias + silu.
// ---------------------------------------------------------------------------
__global__ __launch_bounds__(256) void conv_k(
    const float* __restrict__ xp, const float* __restrict__ cw,
    const float* __restrict__ cb, float* __restrict__ xc, int layer)
{
    const int br = blockIdx.y;
    const long base = (long)br * BT * DINNER;
    const int idx = blockIdx.x * 256 + threadIdx.x;
    const int d = idx & (DINNER - 1);
    const int row = idx >> 8;
    const int t = row & (Tk - 1);
    const float4 w4 = *(const float4*)(cw + ((long)(br * NLAY + layer) * DINNER + d) * 4);
    const float wv[4] = {w4.x, w4.y, w4.z, w4.w};
    float acc = cb[(br * NLAY + layer) * DINNER + d];
    const float* xpb = xp + base + idx;
    #pragma unroll
    for (int k = 0; k < 4; ++k) {
        int tt = t + k - 3;
        if (tt >= 0) acc = fmaf(xpb[(long)(k - 3) * DINNER], wv[k], acc);
    }
    xc[base + idx] = siluf(acc);
}

// ---------------------------------------------------------------------------
// dbl = xc @ W_x (256->40); dt = softplus(dbl[:8] @ W_dt + b_dt); store B,C.
// ---------------------------------------------------------------------------
__global__ __launch_bounds__(256) void dbl_k(
    const float* __restrict__ xc, const float* __restrict__ Wx,
    const float* __restrict__ Wdt, const float* __restrict__ bdt,
    float* __restrict__ dtb, float* __restrict__ bcb, int layer)
{
    const int br = blockIdx.y;
    const float* WxP  = Wx  + (long)(br * NLAY + layer) * DINNER * 40;
    const float* WdtP = Wdt + (long)(br * NLAY + layer) * DTRANK * DINNER;
    const float* bdtP = bdt + (long)(br * NLAY + layer) * DINNER;
    __shared__ float xcs[4][DINNER];
    __shared__ float dbls[4][40];
    const int tid = threadIdx.x;
    const int w = tid >> 6, lane = tid & 63;
    const int row = blockIdx.x * 4 + w;
    const float* xrow = xc + ((long)br * BT + row) * DINNER;
    *(float4*)&xcs[w][lane * 4] = *(const float4*)(xrow + lane * 4);
    __syncthreads();
    if (lane < 40) {
        float dot = 0.f;
        for (int k = 0; k < DINNER; ++k) dot = fmaf(xcs[w][k], WxP[k * 40 + lane], dot);
        dbls[w][lane] = dot;
    }
    __syncthreads();
    float r[DTRANK];
    #pragma unroll
    for (int i = 0; i < DTRANK; ++i) r[i] = dbls[w][i];
    #pragma unroll
    for (int i = 0; i < 4; ++i) {
        int d = i * 64 + lane;
        float tv = bdtP[d];
        #pragma unroll
        for (int k = 0; k < DTRANK; ++k) tv = fmaf(r[k], WdtP[k * DINNER + d], tv);
        dtb[((long)br * BT + row) * DINNER + d] = softplusf(tv);
    }
    if (lane < 32) bcb[((long)br * BT + row) * 32 + lane] = dbls[w][8 + lane];
}

// ---------------------------------------------------------------------------
// Scan pass 1: per-chunk local recurrence from h=0 -> record (h_end[16], sumdt).
// bc slab staged in LDS; t-loop batched by UF with register prefetch.
// Record: recbuf[((br*4+b)*15 + c)*17*256 + slot*256 + d]  (c in [0,15))
// ---------------------------------------------------------------------------
__global__ __launch_bounds__(256) void scan1_k(
    const float* __restrict__ dtb, const float* __restrict__ xcb,
    const float* __restrict__ bcb, const float* __restrict__ Alog,
    float* __restrict__ recbuf, int layer)
{
    const int c = blockIdx.x, b = blockIdx.y, br = blockIdx.z;
    const int d = threadIdx.x;
    const float* Ap = Alog + ((long)(br * NLAY + layer) * DINNER + d) * DSTATE;
    float Aa[16];
    bool pw = true;
    #pragma unroll
    for (int s = 0; s < 16; ++s) {
        Aa[s] = -__expf(Ap[s]);
        pw = pw && (fabsf(Aa[s] + (float)(s + 1)) < 1e-3f);
    }
    const long rbase = (long)br * BT + (long)b * Tk + (long)c * LCH;
    const float* dtp = dtb + rbase * DINNER + d;
    const float* xcp = xcb + rbase * DINNER + d;
    __shared__ float bcs[LCH * 32];      // 8 KB
    {
        const float4* g = (const float4*)(bcb + rbase * 32);
        float4* l = (float4*)bcs;
        l[d] = g[d]; l[d + 256] = g[d + 256];
    }
    float dtc[UF], xcc[UF];
    #pragma unroll
    for (int u = 0; u < UF; ++u) {
        dtc[u] = dtp[(long)u * DINNER];
        xcc[u] = xcp[(long)u * DINNER];
    }
    __syncthreads();
    float h[16];
    #pragma unroll
    for (int s = 0; s < 16; ++s) h[s] = 0.f;
    float sumdt = 0.f;
    for (int base = 0; base < LCH; base += UF) {
        const int nb = (base + UF < LCH) ? base + UF : base;
        float dtn[UF], xcn[UF];
        #pragma unroll
        for (int u = 0; u < UF; ++u) {
            dtn[u] = dtp[(long)(nb + u) * DINNER];
            xcn[u] = xcp[(long)(nb + u) * DINNER];
        }
        #pragma unroll
        for (int u = 0; u < UF; ++u) {
            const int t = base + u;
            const float dtv = dtc[u];
            const float dtxc = dtv * xcc[u];
            sumdt += dtv;
            float dA[16];
            if (pw) dA_pow(__expf(-dtv), dA);
            else    dA_exp(dtv, Aa, dA);
            const float* bcT = bcs + t * 32;     // uniform addr -> broadcast
            #pragma unroll
            for (int s = 0; s < 16; ++s)
                h[s] = fmaf(dA[s], h[s], dtxc * bcT[s]);
        }
        #pragma unroll
        for (int u = 0; u < UF; ++u) { dtc[u] = dtn[u]; xcc[u] = xcn[u]; }
    }
    float* sb = recbuf + (((long)(br * 4 + b) * (NCH - 1) + c) * 17) * 256 + d;
    #pragma unroll
    for (int s = 0; s < 16; ++s) sb[s * 256] = h[s];
    sb[16 * 256] = sumdt;
}

// ---------------------------------------------------------------------------
// Scan pass 2: sequential fold over chunk records -> chunk-start carries.
// Grid 16 blocks (br,b); software-pipelined record loads.
// Carry: carbuf[((br*4+b)*16 + c)*16*256 + s*256 + d]
// ---------------------------------------------------------------------------
__global__ __launch_bounds__(256) void scan2_k(
    const float* __restrict__ Alog, const float* __restrict__ recbuf,
    float* __restrict__ carbuf, int layer)
{
    const int br = blockIdx.x >> 2, b = blockIdx.x & 3;
    const int d = threadIdx.x;
    const float* Ap = Alog + ((long)(br * NLAY + layer) * DINNER + d) * DSTATE;
    float Aa[16];
    bool pw = true;
    #pragma unroll
    for (int s = 0; s < 16; ++s) {
        Aa[s] = -__expf(Ap[s]);
        pw = pw && (fabsf(Aa[s] + (float)(s + 1)) < 1e-3f);
    }
    const float* recB = recbuf + ((long)(br * 4 + b) * (NCH - 1)) * 17 * 256 + d;
    float* carB = carbuf + ((long)(br * 4 + b) * NCH) * 16 * 256 + d;
    float h[16];
    #pragma unroll
    for (int s = 0; s < 16; ++s) h[s] = 0.f;
    float rh[16], rs;
    #pragma unroll
    for (int s = 0; s < 16; ++s) rh[s] = recB[s * 256];
    rs = recB[16 * 256];
    for (int c = 0; c < NCH; ++c) {
        float* car = carB + (long)c * 16 * 256;
        #pragma unroll
        for (int s = 0; s < 16; ++s) car[s * 256] = h[s];
        if (c < NCH - 1) {
            float nh[16], ns = 0.f;
            if (c + 1 < NCH - 1) {
                const float* r2 = recB + (long)(c + 1) * 17 * 256;
                #pragma unroll
                for (int s = 0; s < 16; ++s) nh[s] = r2[s * 256];
                ns = r2[16 * 256];
            } else {
                #pragma unroll
                for (int s = 0; s < 16; ++s) nh[s] = 0.f;
            }
            float P[16];
            if (pw) dA_pow(__expf(-rs), P);
            else    dA_exp(rs, Aa, P);
            #pragma unroll
            for (int s = 0; s < 16; ++s) h[s] = fmaf(h[s], P[s], rh[s]);
            #pragma unroll
            for (int s = 0; s < 16; ++s) rh[s] = nh[s];
            rs = ns;
        }
    }
}

// ---------------------------------------------------------------------------
// Scan pass 3: load chunk-start carry, local recurrence, y, yz = (y+Dp*xc)*silu(z).
// Same LDS/batched structure as pass 1.
// ---------------------------------------------------------------------------
__global__ __launch_bounds__(256) void scan3_k(
    const float* __restrict__ dtb, const float* __restrict__ xcb,
    const float* __restrict__ bcb, const float* __restrict__ zb,
    const float* __restrict__ Alog, const float* __restrict__ Dpar,
    const float* __restrict__ carbuf, float* __restrict__ yz, int layer)
{
    const int c = blockIdx.x, b = blockIdx.y, br = blockIdx.z;
    const int d = threadIdx.x;
    // carry loads first -- longest latency, issued before everything else
    const float* car = carbuf + (((long)(br * 4 + b) * NCH + c) * 16) * 256 + d;
    float h[16];
    #pragma unroll
    for (int s = 0; s < 16; ++s) h[s] = car[s * 256];
    const float* Ap = Alog + ((long)(br * NLAY + layer) * DINNER + d) * DSTATE;
    float Aa[16];
    bool pw = true;
    #pragma unroll
    for (int s = 0; s < 16; ++s) {
        Aa[s] = -__expf(Ap[s]);
        pw = pw && (fabsf(Aa[s] + (float)(s + 1)) < 1e-3f);
    }
    const float Dp = Dpar[(br * NLAY + layer) * DINNER + d];
    const long rbase = (long)br * BT + (long)b * Tk + (long)c * LCH;
    const float* dtp = dtb + rbase * DINNER + d;
    const float* xcp = xcb + rbase * DINNER + d;
    const float* zp  = zb  + rbase * DINNER + d;
    float*       yp  = yz  + rbase * DINNER + d;
    __shared__ float bcs[LCH * 32];      // 8 KB
    {
        const float4* g = (const float4*)(bcb + rbase * 32);
        float4* l = (float4*)bcs;
        l[d] = g[d]; l[d + 256] = g[d + 256];
    }
    float dtc[UF], xcc[UF], zc[UF];
    #pragma unroll
    for (int u = 0; u < UF; ++u) {
        dtc[u] = dtp[(long)u * DINNER];
        xcc[u] = xcp[(long)u * DINNER];
        zc[u]  = zp[(long)u * DINNER];
    }
    __syncthreads();
    for (int base = 0; base < LCH; base += UF) {
        const int nb = (base + UF < LCH) ? base + UF : base;
        float dtn[UF], xcn[UF], zn[UF];
        #pragma unroll
        for (int u = 0; u < UF; ++u) {
            dtn[u] = dtp[(long)(nb + u) * DINNER];
            xcn[u] = xcp[(long)(nb + u) * DINNER];
            zn[u]  = zp[(long)(nb + u) * DINNER];
        }
        #pragma unroll
        for (int u = 0; u < UF; ++u) {
            const int t = base + u;
            const float dtv = dtc[u], xcv = xcc[u];
            const float dtxc = dtv * xcv;
            float dA[16];
            if (pw) dA_pow(__expf(-dtv), dA);
            else    dA_exp(dtv, Aa, dA);
            const float* bcT = bcs + t * 32;     // uniform addr -> broadcast
            #pragma unroll
            for (int s = 0; s < 16; ++s)
                h[s] = fmaf(dA[s], h[s], dtxc * bcT[s]);
            float y0 = 0.f, y1 = 0.f, y2 = 0.f, y3 = 0.f;
            #pragma unroll
            for (int s = 0; s < 16; s += 4) {
                y0 = fmaf(h[s+0], bcT[16+s+0], y0);
                y1 = fmaf(h[s+1], bcT[16+s+1], y1);
                y2 = fmaf(h[s+2], bcT[16+s+2], y2);
                y3 = fmaf(h[s+3], bcT[16+s+3], y3);
            }
            const float y = (y0 + y1) + (y2 + y3) + Dp * xcv;
            yp[(long)t * DINNER] = y * zc[u];
        }
        #pragma unroll
        for (int u = 0; u < UF; ++u) { dtc[u] = dtn[u]; xcc[u] = xcn[u]; zc[u] = zn[u]; }
    }
}

// ---------------------------------------------------------------------------
// mean over T then @ W_op + b_op -> z_t directly into d_out[0..1023].
// ---------------------------------------------------------------------------
__global__ __launch_bounds__(128) void meanop_k(
    const float* __restrict__ hbuf, const float* __restrict__ Wop,
    const float* __restrict__ bop, float* __restrict__ outzt)
{
    const int br = blockIdx.x >> 2, b = blockIdx.x & 3;
    const int tid = threadIdx.x;
    const float* hp = hbuf + ((long)br * BT + (long)b * Tk) * DMODEL + tid;
    float s = 0.f;
    for (int t = 0; t < Tk; ++t) s += hp[(long)t * DMODEL];
    __shared__ float hm[DMODEL];
    hm[tid] = s * (1.0f / Tk);
    __syncthreads();
    if (tid < EMBEDk) {
        float acc = bop[br * EMBEDk + tid];
        for (int k = 0; k < DMODEL; ++k)
            acc = fmaf(hm[k], Wop[(long)br * DMODEL * EMBEDk + k * EMBEDk + tid], acc);
        outzt[br * (Bk * EMBEDk) + b * EMBEDk + tid] = acc;
    }
}

// ---------------------------------------------------------------------------
// Lorentz epilogue.
// ---------------------------------------------------------------------------
__global__ __launch_bounds__(64) void final_k(
    const float* __restrict__ zt, float* __restrict__ out, const float* __restrict__ eff)
{
    const float es = tanhf(eff[0]);
    __shared__ float us[NBR][Bk][EMBEDk];
    const int t = threadIdx.x;
    if (t < 16) {
        const int br = t >> 2, b = t & 3;
        const float* z = zt + br * (Bk * EMBEDk) + b * EMBEDk;
        float n2 = 0.f;
        for (int e = 0; e < EMBEDk; ++e) { float v = z[e] * es; n2 = fmaf(v, v, n2); }
        const float n  = sqrtf(n2);
        const float nc = fminf(fmaxf(n, EPSF), MAXNF);
        const float sc = nc / fmaxf(n, EPSF);
        const float sh = sinhf(nc) / nc;
        const float fac = es * sc * sh;
        float* zh = out + 1024 + br * (Bk * (EMBEDk + 1)) + b * (EMBEDk + 1);
        float sp2 = 0.f;
        for (int e = 0; e < EMBEDk; ++e) {
            float spv = z[e] * fac;
            sp2 = fmaf(spv, spv, sp2);
            zh[1 + e] = spv;
            us[br][b][e] = spv;
        }
        const float t0 = sqrtf(1.f + sp2);
        zh[0] = t0;
        const float dd  = acoshf(fmaxf(t0, 1.f + EPSF));
        const float spn = fmaxf(sqrtf(sp2), EPSF);
        const float rr  = dd / spn;
        for (int e = 0; e < EMBEDk; ++e) us[br][b][e] *= rr;
    }
    __syncthreads();
    if (t < 4) {
        const int b = t;
        float ct[EMBEDk];
        float* cto = out + 2064 + b * EMBEDk;
        for (int e = 0; e < EMBEDk; ++e) {
            float v = us[0][b][e] + us[1][b][e] + us[2][b][e] + us[3][b][e];
            ct[e] = v; cto[e] = v;
        }
        float n2 = 0.f;
        for (int e = 0; e < EMBEDk; ++e) { float v = ct[e] * es; n2 = fmaf(v, v, n2); }
        const float n  = sqrtf(n2);
        const float nc = fminf(fmaxf(n, EPSF), MAXNF);
        const float sc = nc / fmaxf(n, EPSF);
        const float sh = sinhf(nc) / nc;
        const float fac = es * sc * sh;
        float* ch = out + 2320 + b * (EMBEDk + 1);
        float sp2 = 0.f;
        for (int e = 0; e < EMBEDk; ++e) {
            float spv = ct[e] * fac;
            sp2 = fmaf(spv, spv, sp2);
            ch[1 + e] = spv;
        }
        ch[0] = sqrtf(1.f + sp2);
    }
}

extern "C" void kernel_launch(void* const* d_in, const int* in_sizes, int n_in,
                              void* d_out, int out_size, void* d_ws, size_t ws_size,
                              hipStream_t stream)
{
    const float* X[4] = {(const float*)d_in[0], (const float*)d_in[1],
                         (const float*)d_in[2], (const float*)d_in[3]};
    const float* W_ip   = (const float*)d_in[4];
    const float* b_ip   = (const float*)d_in[5];
    const float* W_in   = (const float*)d_in[6];
    const float* conv_w = (const float*)d_in[7];
    const float* conv_b = (const float*)d_in[8];
    const float* W_x    = (const float*)d_in[9];
    const float* W_dt   = (const float*)d_in[10];
    const float* b_dt   = (const float*)d_in[11];
    const float* A_log  = (const float*)d_in[12];
    const float* D_par  = (const float*)d_in[13];
    const float* W_out  = (const float*)d_in[14];
    const float* W_op   = (const float*)d_in[15];
    const float* b_op   = (const float*)d_in[16];
    const float* eff    = (const float*)d_in[17];
    float* out = (float*)d_out;
    float* ws  = (float*)d_ws;

    // workspace layout (floats), ~74 MB
    float* buf_h  = ws;                                  // 4*4096*128 = 2.097M
    float* buf_xp = buf_h  + (long)NBR * BT * DMODEL;    // 4*4096*256 (reused as yz)
    float* buf_z  = buf_xp + (long)NBR * BT * DINNER;
    float* buf_xc = buf_z  + (long)NBR * BT * DINNER;
    float* buf_dt = buf_xc + (long)NBR * BT * DINNER;
    float* buf_bc = buf_dt + (long)NBR * BT * DINNER;    // 4*4096*32
    // scan records + carries alias buf_h (dead between xz-GEMM and W_out-GEMM):
    // records 16*(NCH-1)*17*256 = 1.044M, carries 16*NCH*16*256 = 1.049M;
    // total 2.093M <= 2.097M.  ✓
    float* recbuf = buf_h;
    float* carbuf = buf_h + (long)16 * (NCH - 1) * 17 * 256;

    // input projection per branch: h0 = x @ W_ip + b_ip
    for (int br = 0; br < NBR; ++br) {
        sgemm_k<2><<<dim3(BT / 64, DMODEL / 64, 1), 256, 0, stream>>>(
            X[br], DIN, 0,
            W_ip + (long)br * DIN * DMODEL, DMODEL, 0,
            buf_h + (long)br * BT * DMODEL, nullptr, 0, DMODEL,
            b_ip + br * DMODEL, 0, DIN);
    }

    for (int l = 0; l < NLAY; ++l) {
        // xz = h @ W_in; split -> xp, silu(z)
        sgemm_k<0><<<dim3(BT / 64, (2 * DINNER) / 64, NBR), 256, 0, stream>>>(
            buf_h, DMODEL, (long)BT * DMODEL,
            W_in + (long)l * DMODEL * 2 * DINNER, 2 * DINNER,
            (long)NLAY * DMODEL * 2 * DINNER,
            buf_xp, buf_z, (long)BT * DINNER, 0,
            nullptr, 0, DMODEL);
        // depthwise conv + silu
        conv_k<<<dim3((BT * DINNER) / 256, NBR), 256, 0, stream>>>(
            buf_xp, conv_w, conv_b, buf_xc, l);
        // dbl -> dt, B, C
        dbl_k<<<dim3(BT / 4, NBR), 256, 0, stream>>>(
            buf_xc, W_x, W_dt, b_dt, buf_dt, buf_bc, l);
        // chunked scan: local records -> carry scan -> local w/ carry
        scan1_k<<<dim3(NCH - 1, Bk, NBR), 256, 0, stream>>>(
            buf_dt, buf_xc, buf_bc, A_log, recbuf, l);
        scan2_k<<<16, 256, 0, stream>>>(A_log, recbuf, carbuf, l);
        scan3_k<<<dim3(NCH, Bk, NBR), 256, 0, stream>>>(
            buf_dt, buf_xc, buf_bc, buf_z, A_log, D_par, carbuf, buf_xp, l);
        // h = yz @ W_out
        sgemm_k<1><<<dim3(BT / 64, DMODEL / 64, NBR), 256, 0, stream>>>(
            buf_xp, DINNER, (long)BT * DINNER,
            W_out + (long)l * DINNER * DMODEL, DMODEL,
            (long)NLAY * DINNER * DMODEL,
            buf_h, nullptr, (long)BT * DMODEL, DMODEL,
            nullptr, 0, DINNER);
    }

    meanop_k<<<16, 128, 0, stream>>>(buf_h, W_op, b_op, out);
    final_k<<<1, 64, 0, stream>>>(out, out, eff);
}